// Round 2
// baseline (715.338 us; speedup 1.0000x reference)
//
#include <hip/hip_runtime.h>

// Problem constants (from reference):
constexpr int B     = 32;
constexpr int N_ST  = 8;
constexpr int N_SUB = 256;
constexpr int WIN   = 2048;

// Tile: 512 w x 16 s per block, 256 threads (4 waves).
// Per (t, s-row) a wave issues two back-to-back f4 loads covering a 2 KB
// SEQUENTIAL run (vs 1 KB runs at 8 KB stride in v1/v2) -> better DRAM
// row-buffer locality (H2). Loads are TEMPORAL this round (H1 A/B: v1/v2
// both used nontemporal and tied; nt was never isolated).
constexpr int TW  = 512;
constexpr int TS  = 16;

typedef float f4 __attribute__((ext_vector_type(4)));

__global__ __launch_bounds__(256)
void station_agg_kernel(const float* __restrict__ schedule,  // [B, WIN, N_ST]
                        const float* __restrict__ csi,       // [B, N_ST, N_SUB, WIN]
                        float* __restrict__ out)             // [B, WIN, N_SUB]
{
    __shared__ float sched_t[N_ST][TW];   // 16 KB  [t][w] transposed schedule

    const int s0 = blockIdx.x * TS;
    const int w0 = blockIdx.y * TW;
    const int b  = blockIdx.z;
    const int k  = threadIdx.x;           // 0..255
    const int wv = k >> 6;                // wave 0..3
    const int l  = k & 63;                // lane 0..63

    // Stage schedule[b, w0..w0+511, 0..7] transposed -> sched_t[t][w].
    // Thread k stages w-rows k and k+256 (two f4 loads each, 32 B aligned).
#pragma unroll
    for (int r = 0; r < 2; ++r) {
        const int wr = k + 256 * r;
        const float* sp = schedule + ((size_t)b * WIN + w0 + wr) * N_ST;
        const f4 a = *(const f4*)sp;
        const f4 c = *(const f4*)(sp + 4);
        sched_t[0][wr] = a.x; sched_t[1][wr] = a.y;
        sched_t[2][wr] = a.z; sched_t[3][wr] = a.w;
        sched_t[4][wr] = c.x; sched_t[5][wr] = c.y;
        sched_t[6][wr] = c.z; sched_t[7][wr] = c.w;
    }
    __syncthreads();

    // Wave wv owns s rows srow..srow+3; lane l owns w = w0+4l..4l+3 (chunk 0)
    // and w0+1024/4... i.e. +256 floats (chunk 1). acc[c][j], c=chunk, j=s.
    f4 acc[2][4];
#pragma unroll
    for (int c = 0; c < 2; ++c)
#pragma unroll
        for (int j = 0; j < 4; ++j) acc[c][j] = (f4)(0.0f);

    const size_t bbase = (size_t)b * N_ST * N_SUB * WIN;
    const int    srow  = s0 + 4 * wv;

#pragma unroll
    for (int t = 0; t < N_ST; ++t) {
        // b128 LDS reads, lanes 16B-contiguous -> canonical conflict-free.
        const f4 sv0 = *(const f4*)&sched_t[t][4 * l];
        const f4 sv1 = *(const f4*)&sched_t[t][4 * l + 256];
        const float* cp = csi + bbase
                        + ((size_t)t * N_SUB + srow) * WIN + (w0 + 4 * l);
#pragma unroll
        for (int j = 0; j < 4; ++j) {
            // Two wave-instrs = one 2 KB sequential run per (t, s-row).
            const f4 c0 = *(const f4*)(cp + (size_t)j * WIN);
            const f4 c1 = *(const f4*)(cp + (size_t)j * WIN + 256);
            acc[0][j] += c0 * sv0;
            acc[1][j] += c1 * sv1;
        }
    }

    // In-register 4x4 transpose + direct f4 stores along s (proven equal to
    // LDS-transpose epilogue in v1/v2 A/B). acc[c][j][col] = value at
    // (s = srow+j, w = w0 + 4l + 256c + col). The 4 waves' 16 B quarters of
    // each 64 B out line merge in L2 (same block, same XCD).
#pragma unroll
    for (int c = 0; c < 2; ++c) {
        const int wbase = w0 + 4 * l + 256 * c;
        float* op = out + ((size_t)b * WIN + wbase) * N_SUB + srow;
#pragma unroll
        for (int col = 0; col < 4; ++col) {
            f4 o;
            o.x = acc[c][0][col];
            o.y = acc[c][1][col];
            o.z = acc[c][2][col];
            o.w = acc[c][3][col];
            *(f4*)(op + (size_t)col * N_SUB) = o;
        }
    }
}

extern "C" void kernel_launch(void* const* d_in, const int* in_sizes, int n_in,
                              void* d_out, int out_size, void* d_ws, size_t ws_size,
                              hipStream_t stream) {
    const float* schedule = (const float*)d_in[0];  // [B, WIN, N_ST]
    const float* csi      = (const float*)d_in[1];  // [B, N_ST, N_SUB, WIN]
    float* out            = (float*)d_out;          // [B, WIN, N_SUB]

    dim3 grid(N_SUB / TS, WIN / TW, B);   // 16 x 4 x 32 = 2048 blocks
    dim3 block(256);
    station_agg_kernel<<<grid, block, 0, stream>>>(schedule, csi, out);
}

// Round 3
// 680.537 us; speedup vs baseline: 1.0511x; 1.0511x over previous
//
#include <hip/hip_runtime.h>

// Problem constants (from reference):
constexpr int B     = 32;
constexpr int N_ST  = 8;
constexpr int N_SUB = 256;
constexpr int WIN   = 2048;

// Tile: 256 w x 16 s per block, 256 threads (4 waves).
// Every wave csi load = one contiguous 1 KB segment (64 lanes x float4).
//
// A/B history (this session):
//   v1 (this config):            670.8 us   <- best, restored here
//   v2 nt-loads/temporal-stores,
//      register epilogue:        688.1 us
//   v3 temporal everything,
//      TW=512:                   715.3 us
// Conclusion: nontemporal on BOTH the 537 MB read-once csi stream and the
// write-once out stream is worth ~20-27 us each (L2 pollution / merge
// pressure); structural changes (load batching, epilogue style, tile
// shape) are neutral. Keep nt + LDS-transpose epilogue (full 64 B store
// segments per wave instruction).
constexpr int TW  = 256;
constexpr int TS  = 16;
constexpr int STR = 260;   // tile2 row stride (floats): 256+4 keeps float4
                           // alignment; epilogue scalar reads land 2-way (free)

typedef float f4 __attribute__((ext_vector_type(4)));

__global__ __launch_bounds__(256)
void station_agg_kernel(const float* __restrict__ schedule,  // [B, WIN, N_ST]
                        const float* __restrict__ csi,       // [B, N_ST, N_SUB, WIN]
                        float* __restrict__ out)             // [B, WIN, N_SUB]
{
    __shared__ float sched_t[N_ST][TW];   // 8 KB   [t][w] transposed schedule
    __shared__ float tile2[TS * STR];     // 16.6KB [s][w+pad] transpose buffer

    const int s0 = blockIdx.x * TS;
    const int w0 = blockIdx.y * TW;
    const int b  = blockIdx.z;
    const int k  = threadIdx.x;           // 0..255
    const int wv = k >> 6;                // wave 0..3
    const int l  = k & 63;                // lane 0..63

    // Stage schedule[b, w0..w0+255, 0..7] transposed -> sched_t[t][w].
    // Thread k loads w-row k's 8 weights (two float4s, 32 B aligned).
    // (Schedule tile is re-read by all 16 s-blocks -> temporal is correct.)
    {
        const float* sp = schedule + ((size_t)b * WIN + w0 + k) * N_ST;
        const f4 a = *(const f4*)sp;
        const f4 c = *(const f4*)(sp + 4);
        sched_t[0][k] = a.x; sched_t[1][k] = a.y;
        sched_t[2][k] = a.z; sched_t[3][k] = a.w;
        sched_t[4][k] = c.x; sched_t[5][k] = c.y;
        sched_t[6][k] = c.z; sched_t[7][k] = c.w;
    }
    __syncthreads();

    // Wave wv owns s rows s0+4*wv+j (j=0..3); lane l owns w = w0+4l..4l+3.
    f4 acc[4];
#pragma unroll
    for (int j = 0; j < 4; ++j) acc[j] = (f4)(0.0f);

    const size_t bbase = (size_t)b * N_ST * N_SUB * WIN;
#pragma unroll
    for (int t = 0; t < N_ST; ++t) {
        // b128 LDS read, lanes 16B-contiguous -> conflict-free.
        const f4 sv = *(const f4*)&sched_t[t][4 * l];
        const float* cp = csi + bbase
                        + ((size_t)t * N_SUB + (s0 + 4 * wv)) * WIN
                        + (w0 + 4 * l);
#pragma unroll
        for (int j = 0; j < 4; ++j) {
            // One contiguous 1 KB segment per wave instruction; csi is
            // read-once (537 MB) -> nontemporal, don't pollute L2.
            const f4 c = __builtin_nontemporal_load((const f4*)(cp + (size_t)j * WIN));
            acc[j] += c * sv;
        }
    }

    // Transpose via LDS: tile2[s][w], b128 writes lanes-contiguous -> 0-conflict.
#pragma unroll
    for (int j = 0; j < 4; ++j)
        *(f4*)&tile2[(4 * wv + j) * STR + 4 * l] = acc[j];
    __syncthreads();

    // Coalesced out stores: per wave instr, 16 w-rows x 16 s = 16 aligned
    // 64B lines, each FULLY covered -> nt store is safe (no RMW, no L2
    // merge dependence). Epilogue LDS reads: 2-way bank aliasing (free).
#pragma unroll
    for (int m = 0; m < 4; ++m) {
        const int wrow = 16 * wv + (l >> 2) + 64 * m;  // 0..255
        const int sl   = 4 * (l & 3);                  // 0,4,8,12
        f4 o;
        o.x = tile2[(sl + 0) * STR + wrow];
        o.y = tile2[(sl + 1) * STR + wrow];
        o.z = tile2[(sl + 2) * STR + wrow];
        o.w = tile2[(sl + 3) * STR + wrow];
        __builtin_nontemporal_store(o,
            (f4*)(out + ((size_t)b * WIN + (w0 + wrow)) * N_SUB + (s0 + sl)));
    }
}

extern "C" void kernel_launch(void* const* d_in, const int* in_sizes, int n_in,
                              void* d_out, int out_size, void* d_ws, size_t ws_size,
                              hipStream_t stream) {
    const float* schedule = (const float*)d_in[0];  // [B, WIN, N_ST]
    const float* csi      = (const float*)d_in[1];  // [B, N_ST, N_SUB, WIN]
    float* out            = (float*)d_out;          // [B, WIN, N_SUB]

    dim3 grid(N_SUB / TS, WIN / TW, B);   // 16 x 8 x 32 = 4096 blocks
    dim3 block(256);
    station_agg_kernel<<<grid, block, 0, stream>>>(schedule, csi, out);
}